// Round 15
// baseline (258.198 us; speedup 1.0000x reference)
//
#include <hip/hip_runtime.h>
#include <hip/hip_bf16.h>

typedef __attribute__((ext_vector_type(8))) short s16x8;
typedef __attribute__((ext_vector_type(4))) float f32x4;
typedef unsigned short u16;
typedef unsigned int u32;

constexpr int NN = 50000;
constexpr int NE = 600000;
constexpr int NIDX = 10000;

__device__ inline u16 f2b(float x) {
    __hip_bfloat16 h = __float2bfloat16(x);
    return *(u16*)&h;
}

__device__ inline s16x8 pack8(float4 a, float4 b) {
    s16x8 r;
    r[0] = (short)f2b(a.x); r[1] = (short)f2b(a.y);
    r[2] = (short)f2b(a.z); r[3] = (short)f2b(a.w);
    r[4] = (short)f2b(b.x); r[5] = (short)f2b(b.y);
    r[6] = (short)f2b(b.z); r[7] = (short)f2b(b.w);
    return r;
}

// async global->LDS DMA, 16B per lane: LDS dst = wave-uniform base + lane*16.
__device__ inline void gl_lds16(const void* gptr, void* lptr) {
    __builtin_amdgcn_global_load_lds(
        (const __attribute__((address_space(1))) char*)gptr,
        (__attribute__((address_space(3))) char*)lptr, 16, 0, 0);
}

template <int N> __device__ inline void vmwait() {
    asm volatile("s_waitcnt vmcnt(%0)" :: "n"(N) : "memory");
}
__device__ inline void barrier_nodrains() {
    __builtin_amdgcn_sched_barrier(0);
    __builtin_amdgcn_s_barrier();
    __builtin_amdgcn_sched_barrier(0);
}

// ---------------- fused setup: padvf64 | win832 | bcomb | wrg1 | wrg2 | zeros | mark-zero ----------------

__global__ void k_setup(const float* __restrict__ vf,
                        const float* __restrict__ fc1w, const float* __restrict__ fc2w,
                        const float* __restrict__ reluw,
                        const float* __restrict__ fc1b, const float* __restrict__ fc2b,
                        const float* __restrict__ relub,
                        const float* __restrict__ w1rel, const float* __restrict__ w1root,
                        const float* __restrict__ w2rel, const float* __restrict__ w2root,
                        float* __restrict__ vfp, u16* __restrict__ WTin,
                        float* __restrict__ bcomb, u16* __restrict__ WT1, u16* __restrict__ WT2,
                        int* __restrict__ zero_region, int* __restrict__ mark) {
    int b = blockIdx.x, t = threadIdx.x;
    if (b < 12500) {                             // padvf: NN*64 = 3.2M, cols 16..63 zero
        int i = b * 256 + t;
        int n = i >> 6, c = i & 63;
        vfp[i] = c < 16 ? vf[n * 16 + c] : 0.f;
    } else if (b < 13332) {                      // win: k = b-12500 in [0,832); k>=784 -> 0
        if (t < 128) {
            int k = b - 12500, c = t;
            float s = 0.f;
            if (k < 768) {
                for (int j = 0; j < 128; ++j) s += fc2w[k * 128 + j] * reluw[(128 + j) * 128 + c];
            } else if (k < 784) {
                int kk = k - 768;
                for (int j = 0; j < 128; ++j) s += fc1w[kk * 128 + j] * reluw[j * 128 + c];
            }
            WTin[c * 832 + k] = f2b(s);
        }
    } else if (b == 13332) {                     // bcomb
        if (t < 128) {
            int c = t;
            float s = relub[c];
            for (int j = 0; j < 128; ++j) {
                s += fc1b[j] * reluw[j * 128 + c];
                s += fc2b[j] * reluw[(128 + j) * 128 + c];
            }
            bcomb[c] = s;
        }
    } else if (b < 13845) {                      // wrg1: s = b-13333 in [0,512)
        if (t < 128) {
            int s = b - 13333, c = t;
            float v = (s < 384) ? w1rel[(size_t)s * 128 + c] : w1root[(size_t)(s - 384) * 128 + c];
            WT1[c * 512 + s] = f2b(v);
        }
    } else if (b < 14357) {                      // wrg2
        if (t < 128) {
            int s = b - 13845, c = t;
            float v = (s < 384) ? w2rel[(size_t)s * 128 + c] : w2root[(size_t)(s - 384) * 128 + c];
            WT2[c * 512 + s] = f2b(v);
        }
    } else if (b < 15334) {                      // zero counters region: 250002 ints
        int i = (b - 14357) * 256 + t;
        if (i < 250002) zero_region[i] = 0;
    } else {                                     // zero mark[NN]
        int i = (b - 15334) * 256 + t;
        if (i < NN) mark[i] = 0;
    }
}

// ---------------- CSR hist + idx mark/compact ----------------

__global__ void k_hist_mark(const int* __restrict__ ei, const int* __restrict__ et,
                            int* __restrict__ deg_node, int* __restrict__ deg_rel,
                            const int* __restrict__ idx, int* __restrict__ mark,
                            int* __restrict__ cnt2, int* __restrict__ list) {
    int b = blockIdx.x;
    if (b < 2344) {
        int e = b * 256 + threadIdx.x;
        if (e < NE) {
            int dst = ei[NE + e];
            int r = et[e];
            atomicAdd(&deg_node[dst], 1);
            atomicAdd(&deg_rel[r * NN + dst], 1);
        }
    } else {
        int i = (b - 2344) * 256 + threadIdx.x;
        if (i < NIDX) {
            int n = idx[i];
            if (atomicExch(&mark[n], 1) == 0) {
                int p = atomicAdd(cnt2, 1);
                list[p] = n;
            }
        }
    }
}

// ---------------- alloc (CSR offsets) + norm ----------------

__global__ void k_alloc_norm(const int* __restrict__ deg_node, int* __restrict__ baseoff,
                             int* __restrict__ counter, const int* __restrict__ deg_rel,
                             float* __restrict__ normf) {
    int b = blockIdx.x;
    if (b < 196) {
        int i = b * 256 + threadIdx.x;
        int lane = threadIdx.x & 63;
        int d = (i < NN) ? deg_node[i] : 0;
        int scan = d;
        for (int off = 1; off < 64; off <<= 1) {
            int t = __shfl_up(scan, off, 64);
            if (lane >= off) scan += t;
        }
        int total = __shfl(scan, 63, 64);
        int wbase = 0;
        if (lane == 63) wbase = atomicAdd(counter, total);
        wbase = __shfl(wbase, 63, 64);
        if (i < NN) baseoff[i] = wbase + scan - d;
    } else {
        int i = (b - 196) * 256 + threadIdx.x;
        if (i < 3 * NN) normf[i] = 1.0f / (float)max(deg_rel[i], 1);
    }
}

__global__ void k_fill(const int* __restrict__ ei, const int* __restrict__ et,
                       const int* __restrict__ baseoff, int* __restrict__ cursor,
                       int* __restrict__ elist) {
    int e = blockIdx.x * 256 + threadIdx.x;
    if (e >= NE) return;
    int dst = ei[NE + e];
    int src = ei[e];
    int r = et[e];
    int pos = atomicAdd(&cursor[dst], 1);
    elist[baseoff[dst] + pos] = src | (r << 20);
}

// ---------------- aggregation (round-11 serial form, measured best) ----------------

__global__ __launch_bounds__(64) void k_agg(const u16* __restrict__ x, u16* __restrict__ A,
                                            const int* __restrict__ elist,
                                            const int* __restrict__ baseoff,
                                            const int* __restrict__ deg_node,
                                            const float* __restrict__ normf) {
    int n = blockIdx.x;
    int lane = threadIdx.x;
    float a0x = 0.f, a0y = 0.f, a1x = 0.f, a1y = 0.f, a2x = 0.f, a2y = 0.f;
    int nb = deg_node[n];
    int b0 = baseoff[n];
    for (int i = 0; i < nb; ++i) {
        int p = elist[b0 + i];
        int src = p & 0xFFFFF;
        int r = p >> 20;
        u32 pair = *(const u32*)&x[(size_t)src * 128 + lane * 2];
        float vx = __uint_as_float((pair & 0xFFFFu) << 16);
        float vy = __uint_as_float((pair >> 16) << 16);
        if (r == 0)      { a0x += vx; a0y += vy; }
        else if (r == 1) { a1x += vx; a1y += vy; }
        else             { a2x += vx; a2y += vy; }
    }
    float n0 = normf[n], n1 = normf[NN + n], n2 = normf[2 * NN + n];
    u32* Ao = (u32*)&A[(size_t)n * 384];
    Ao[lane]        = (u32)f2b(a0x * n0) | ((u32)f2b(a0y * n0) << 16);
    Ao[64 + lane]   = (u32)f2b(a1x * n1) | ((u32)f2b(a1y * n1) << 16);
    Ao[128 + lane]  = (u32)f2b(a2x * n2) | ((u32)f2b(a2y * n2) << 16);
}

// layer-2 aggregation: only rows in list[0..cnt2), output compacted
__global__ __launch_bounds__(64) void k_agg2(const u16* __restrict__ x, u16* __restrict__ A2buf,
                                             const int* __restrict__ elist,
                                             const int* __restrict__ baseoff,
                                             const int* __restrict__ deg_node,
                                             const float* __restrict__ normf,
                                             const int* __restrict__ list,
                                             const int* __restrict__ cnt2) {
    int i = blockIdx.x;
    if (i >= *cnt2) return;
    int n = list[i];
    int lane = threadIdx.x;
    float a0x = 0.f, a0y = 0.f, a1x = 0.f, a1y = 0.f, a2x = 0.f, a2y = 0.f;
    int nb = deg_node[n];
    int b0 = baseoff[n];
    for (int e = 0; e < nb; ++e) {
        int p = elist[b0 + e];
        int src = p & 0xFFFFF;
        int r = p >> 20;
        u32 pair = *(const u32*)&x[(size_t)src * 128 + lane * 2];
        float vx = __uint_as_float((pair & 0xFFFFu) << 16);
        float vy = __uint_as_float((pair >> 16) << 16);
        if (r == 0)      { a0x += vx; a0y += vy; }
        else if (r == 1) { a1x += vx; a1y += vy; }
        else             { a2x += vx; a2y += vy; }
    }
    float n0 = normf[n], n1 = normf[NN + n], n2 = normf[2 * NN + n];
    u32* Ao = (u32*)&A2buf[(size_t)i * 384];
    Ao[lane]        = (u32)f2b(a0x * n0) | ((u32)f2b(a0y * n0) << 16);
    Ao[64 + lane]   = (u32)f2b(a1x * n1) | ((u32)f2b(a1y * n1) << 16);
    Ao[128 + lane]  = (u32)f2b(a2x * n2) | ((u32)f2b(a2y * n2) << 16);
}

// ---------------- GEMM body: BK=64 (2 k32 sub-tiles per stage), 3 LDS buffers,
// depth-2 prefetch, counted vmcnt at no-drain barriers. Steps = KT32/2.
// LIST mode: dynamic N=*cntp, A2 and output rows indirected through list[] ----------------

template <typename TA, int K1T, int K2T, bool LRELU, bool LIST>
__device__ __forceinline__ void gemm_body(const TA* __restrict__ A1, int lda1,
                                          const TA* __restrict__ A2, int lda2,
                                          const u16* __restrict__ WT, int ldwt,
                                          const float* __restrict__ bias,
                                          u16* __restrict__ out, int Nin,
                                          const int* __restrict__ list,
                                          const int* __restrict__ cntp) {
    constexpr int KT32 = K1T + K2T;           // number of k32 tiles (even)
    constexpr int NST = KT32 / 2;             // BK64 steps
    constexpr int ABYTES = 64 * 32 * (int)sizeof(TA);   // per k32 sub-tile
    constexpr int SUB = ABYTES + 8192;        // sub-tile total (A + B)
    constexpr int TILEB = 2 * SUB;            // per buffer (BK=64)
    constexpr int OPW = (sizeof(TA) == 4) ? 8 : 6;   // DMA instrs per wave per BK64 stage
    __shared__ alignas(128) char lds[3][TILEB];

    const int N = LIST ? *cntp : Nin;
    const int m0 = blockIdx.x * 64;
    if (LIST && m0 >= N) return;   // uniform whole-block exit, before any barrier

    const int tid = threadIdx.x;
    const int w = tid >> 6, lane = tid & 63;
    const int wr = w >> 1, wc = w & 1;
    const int lq = lane >> 4, lr = lane & 15;

    auto stage32 = [&](int kt, char* base) {
        if constexpr (sizeof(TA) == 4) {
#pragma unroll
            for (int jj = 0; jj < 2; ++jj) {
                int row = w * 16 + jj * 8 + (lane >> 3);
                int s = lane & 7;
                int chunk = s ^ (row & 7);
                int rg = min(m0 + row, N - 1);
                const float* g;
                if (kt < K1T) g = (const float*)A1 + (size_t)rg * lda1 + kt * 32 + chunk * 4;
                else          g = (const float*)A2 + (size_t)rg * lda2 + (kt - K1T) * 32 + chunk * 4;
                gl_lds16(g, base + w * 2048 + jj * 1024);
            }
        } else {
            int row = w * 16 + (lane >> 2);
            int s = lane & 3;
            int chunk = s ^ ((row >> 1) & 3);
            int rg = min(m0 + row, N - 1);
            const u16* g;
            if (kt < K1T) {
                g = (const u16*)A1 + (size_t)rg * lda1 + kt * 32 + chunk * 8;
            } else {
                int node = LIST ? list[rg] : rg;
                g = (const u16*)A2 + (size_t)node * lda2 + (kt - K1T) * 32 + chunk * 8;
            }
            gl_lds16(g, base + w * 1024);
        }
#pragma unroll
        for (int jj = 0; jj < 2; ++jj) {
            int col = w * 32 + jj * 16 + (lane >> 2);
            int s = lane & 3;
            int chunk = s ^ ((col >> 1) & 3);
            const u16* g = WT + (size_t)col * ldwt + kt * 32 + chunk * 8;
            gl_lds16(g, base + ABYTES + w * 2048 + jj * 1024);
        }
    };
    auto stage = [&](int j) {
        char* bb = lds[j % 3];
        stage32(2 * j, bb);
        stage32(2 * j + 1, bb + SUB);
    };

    f32x4 acc[2][4] = {};

    auto compute32 = [&](char* base) {
        s16x8 af[2];
#pragma unroll
        for (int i = 0; i < 2; ++i) {
            int row = wr * 32 + i * 16 + lr;
            if constexpr (sizeof(TA) == 4) {
                int m = row & 7;
                float4 f0 = *(const float4*)(base + row * 128 + (((2 * lq) ^ m) * 16));
                float4 f1 = *(const float4*)(base + row * 128 + (((2 * lq + 1) ^ m) * 16));
                af[i] = pack8(f0, f1);
            } else {
                int sl = lq ^ ((row >> 1) & 3);
                af[i] = *(const s16x8*)(base + row * 64 + sl * 16);
            }
        }
#pragma unroll
        for (int j4 = 0; j4 < 4; ++j4) {
            int col = wc * 64 + j4 * 16 + lr;
            int sl = lq ^ ((col >> 1) & 3);
            s16x8 bf = *(const s16x8*)(base + ABYTES + col * 64 + sl * 16);
#pragma unroll
            for (int i = 0; i < 2; ++i)
                acc[i][j4] = __builtin_amdgcn_mfma_f32_16x16x32_bf16(af[i], bf, acc[i][j4], 0, 0, 0);
        }
    };
    auto compute = [&](int j) {
        char* bb = lds[j % 3];
        compute32(bb);
        compute32(bb + SUB);
    };

    stage(0); stage(1);
#pragma unroll 1
    for (int j = 0; j < NST - 1; ++j) {
        vmwait<OPW>();             // stage(j) landed; stage(j+1) stays in flight
        barrier_nodrains();
        if (j + 2 < NST) stage(j + 2);
        compute(j);
    }
    vmwait<0>();
    barrier_nodrains();
    compute(NST - 1);

#pragma unroll
    for (int i = 0; i < 2; ++i) {
#pragma unroll
        for (int q = 0; q < 4; ++q) {
            int grow = m0 + wr * 32 + i * 16 + lq * 4 + q;
            if (grow < N) {
                int orow = LIST ? list[grow] : grow;
#pragma unroll
                for (int j = 0; j < 4; ++j) {
                    int col = wc * 64 + j * 16 + lr;
                    float v = acc[i][j][q] + bias[col];
                    if (LRELU) v = v > 0.f ? v : 0.01f * v;
                    out[(size_t)orow * 128 + col] = f2b(v);
                }
            }
        }
    }
}

__global__ __launch_bounds__(256) void k_gemm_in(const float* __restrict__ A1, int lda1,
                                                 const float* __restrict__ A2, int lda2,
                                                 const u16* __restrict__ WT, int ldwt,
                                                 const float* __restrict__ bias,
                                                 u16* __restrict__ out, int N) {
    gemm_body<float, 24, 2, true, false>(A1, lda1, A2, lda2, WT, ldwt, bias, out, N, nullptr, nullptr);
}
__global__ __launch_bounds__(256) void k_gemm_r1(const u16* __restrict__ A1, int lda1,
                                                 const u16* __restrict__ A2, int lda2,
                                                 const u16* __restrict__ WT, int ldwt,
                                                 const float* __restrict__ bias,
                                                 u16* __restrict__ out, int N) {
    gemm_body<u16, 12, 4, false, false>(A1, lda1, A2, lda2, WT, ldwt, bias, out, N, nullptr, nullptr);
}
__global__ __launch_bounds__(256) void k_gemm_r2(const u16* __restrict__ A1, int lda1,
                                                 const u16* __restrict__ A2, int lda2,
                                                 const u16* __restrict__ WT, int ldwt,
                                                 const float* __restrict__ bias,
                                                 u16* __restrict__ out,
                                                 const int* __restrict__ list,
                                                 const int* __restrict__ cnt2) {
    gemm_body<u16, 12, 4, false, true>(A1, lda1, A2, lda2, WT, ldwt, bias, out, NIDX, list, cnt2);
}

// ---------------- final gather + classifier ----------------

__global__ __launch_bounds__(256) void k_out(const u16* __restrict__ h, const int* __restrict__ idx,
                                             const float* __restrict__ fc3w,
                                             const float* __restrict__ fc3b,
                                             float* __restrict__ out, int M) {
    int w = threadIdx.x >> 6;
    int lane = threadIdx.x & 63;
    int row = blockIdx.x * 4 + w;
    if (row >= M) return;
    int n = idx[row];
    u32 pair = *(const u32*)&h[(size_t)n * 128 + lane * 2];
    float v0 = __uint_as_float((pair & 0xFFFFu) << 16);
    float v1 = __uint_as_float((pair >> 16) << 16);
    float4 wv = *(const float4*)&fc3w[lane * 4];
    float s0 = v0 * wv.x + v1 * wv.z;
    float s1 = v0 * wv.y + v1 * wv.w;
    for (int off = 32; off >= 1; off >>= 1) {
        s0 += __shfl_xor(s0, off, 64);
        s1 += __shfl_xor(s1, off, 64);
    }
    if (lane == 0) {
        out[row * 2] = s0 + fc3b[0];
        out[row * 2 + 1] = s1 + fc3b[1];
    }
}

// ---------------- launch ----------------

extern "C" void kernel_launch(void* const* d_in, const int* in_sizes, int n_in,
                              void* d_out, int out_size, void* d_ws, size_t ws_size,
                              hipStream_t stream) {
    const float* vf    = (const float*)d_in[0];
    const float* tf    = (const float*)d_in[1];
    const float* fc1w  = (const float*)d_in[2];
    const float* fc1b  = (const float*)d_in[3];
    const float* fc2w  = (const float*)d_in[4];
    const float* fc2b  = (const float*)d_in[5];
    const float* reluw = (const float*)d_in[6];
    const float* relub = (const float*)d_in[7];
    const float* w1rel = (const float*)d_in[8];
    const float* w1root= (const float*)d_in[9];
    const float* b1    = (const float*)d_in[10];
    const float* w2rel = (const float*)d_in[11];
    const float* w2root= (const float*)d_in[12];
    const float* b2    = (const float*)d_in[13];
    const float* fc3w  = (const float*)d_in[14];
    const float* fc3b  = (const float*)d_in[15];
    const int* ei      = (const int*)d_in[16];
    const int* et      = (const int*)d_in[17];
    const int* idx     = (const int*)d_in[18];
    float* out = (float*)d_out;

    char* W = (char*)d_ws;
    const size_t OFF_WTIN  = 0;          // 128*832*2 = 212992
    const size_t OFF_WT1   = 212992;     // 131072
    const size_t OFF_WT2   = 344064;     // 131072
    const size_t OFF_BCOMB = 475136;     // 512
    const size_t OFF_DEGN  = 475648;     // zero region: degn|cur|degr|cnt|cnt2 = 250002 ints
    const size_t OFF_CUR   = 675648;
    const size_t OFF_DEGR  = 875648;
    const size_t OFF_CNT   = 1475648;
    const size_t OFF_CNT2  = 1475652;
    const size_t OFF_BASE  = 1475904;
    const size_t OFF_NORM  = 1675904;
    const size_t OFF_ELIST = 2275904;
    const size_t OFF_A     = 4675904;    // 38400000
    const size_t OFF_H0    = 43075904;   // 12800000
    const size_t OFF_H1    = 55875904;   // 12800000
    const size_t OFF_H2    = 68675904;   // 12800000
    const size_t OFF_VFPAD = 81475904;   // NN*64*4 = 12800000
    const size_t OFF_LIST  = 94275904;   // 40000
    const size_t OFF_A2    = 94315904;   // 7680000
    const size_t OFF_MARK  = 101995904;  // 200000 -> total 102195904 (~102MB, ws ~600MB)

    u16* WTin   = (u16*)(W + OFF_WTIN);
    u16* WT1    = (u16*)(W + OFF_WT1);
    u16* WT2    = (u16*)(W + OFF_WT2);
    float* bcomb= (float*)(W + OFF_BCOMB);
    int* degn   = (int*)(W + OFF_DEGN);
    int* cur    = (int*)(W + OFF_CUR);
    int* degr   = (int*)(W + OFF_DEGR);
    int* cnt    = (int*)(W + OFF_CNT);
    int* cnt2   = (int*)(W + OFF_CNT2);
    int* base   = (int*)(W + OFF_BASE);
    float* normf= (float*)(W + OFF_NORM);
    int* elist  = (int*)(W + OFF_ELIST);
    u16* Abuf   = (u16*)(W + OFF_A);
    u16* h0     = (u16*)(W + OFF_H0);
    u16* h1     = (u16*)(W + OFF_H1);
    u16* h2     = (u16*)(W + OFF_H2);
    float* vfp  = (float*)(W + OFF_VFPAD);
    int* list   = (int*)(W + OFF_LIST);
    u16* A2buf  = (u16*)(W + OFF_A2);
    int* mark   = (int*)(W + OFF_MARK);

    const int GRID_GEMM = (NN + 63) / 64;      // 782
    const int GRID_G2   = (NIDX + 63) / 64;    // 157

    // 1. fused setup
    k_setup<<<15530, 256, 0, stream>>>(vf, fc1w, fc2w, reluw, fc1b, fc2b, relub,
                                       w1rel, w1root, w2rel, w2root,
                                       vfp, WTin, bcomb, WT1, WT2, degn, mark);

    // 2. fused input GEMM (K=832 padded, 13 BK64 steps)
    k_gemm_in<<<GRID_GEMM, 256, 0, stream>>>(tf, 768, vfp, 64, WTin, 832, bcomb, h0, NN);

    // 3. CSR build + idx mark/compact
    k_hist_mark<<<2384, 256, 0, stream>>>(ei, et, degn, degr, idx, mark, cnt2, list);
    k_alloc_norm<<<782, 256, 0, stream>>>(degn, base, cnt, degr, normf);
    k_fill<<<(NE + 255) / 256, 256, 0, stream>>>(ei, et, base, cur, elist);

    // 4. RGCN layer 1 (full, 8 BK64 steps)
    k_agg<<<NN, 64, 0, stream>>>(h0, Abuf, elist, base, degn, normf);
    k_gemm_r1<<<GRID_GEMM, 256, 0, stream>>>(Abuf, 384, h0, 128, WT1, 512, b1, h1, NN);

    // 5. RGCN layer 2 (only idx rows, 8 BK64 steps)
    k_agg2<<<NIDX, 64, 0, stream>>>(h1, A2buf, elist, base, degn, normf, list, cnt2);
    k_gemm_r2<<<GRID_G2, 256, 0, stream>>>(A2buf, 384, h1, 128, WT2, 512, b2, h2, list, cnt2);

    // 6. classifier on gathered rows
    k_out<<<(NIDX + 3) / 4, 256, 0, stream>>>(h2, idx, fc3w, fc3b, out, NIDX);
}

// Round 17
// 250.807 us; speedup vs baseline: 1.0295x; 1.0295x over previous
//
#include <hip/hip_runtime.h>
#include <hip/hip_bf16.h>

typedef __attribute__((ext_vector_type(8))) short s16x8;
typedef __attribute__((ext_vector_type(4))) float f32x4;
typedef unsigned short u16;
typedef unsigned int u32;

constexpr int NN = 50000;
constexpr int NE = 600000;
constexpr int NIDX = 10000;

__device__ inline u16 f2b(float x) {
    __hip_bfloat16 h = __float2bfloat16(x);
    return *(u16*)&h;
}

__device__ inline s16x8 pack8(float4 a, float4 b) {
    s16x8 r;
    r[0] = (short)f2b(a.x); r[1] = (short)f2b(a.y);
    r[2] = (short)f2b(a.z); r[3] = (short)f2b(a.w);
    r[4] = (short)f2b(b.x); r[5] = (short)f2b(b.y);
    r[6] = (short)f2b(b.z); r[7] = (short)f2b(b.w);
    return r;
}

// async global->LDS DMA, 16B per lane: LDS dst = wave-uniform base + lane*16.
__device__ inline void gl_lds16(const void* gptr, void* lptr) {
    __builtin_amdgcn_global_load_lds(
        (const __attribute__((address_space(1))) char*)gptr,
        (__attribute__((address_space(3))) char*)lptr, 16, 0, 0);
}

template <int N> __device__ inline void vmwait() {
    asm volatile("s_waitcnt vmcnt(%0)" :: "n"(N) : "memory");
}
__device__ inline void barrier_nodrains() {
    __builtin_amdgcn_sched_barrier(0);
    __builtin_amdgcn_s_barrier();
    __builtin_amdgcn_sched_barrier(0);
}

// ---------------- fused setup: padvf | win | bcomb | wrg1 | wrg2 | zeros | mark-zero ----------------

__global__ void k_setup(const float* __restrict__ vf,
                        const float* __restrict__ fc1w, const float* __restrict__ fc2w,
                        const float* __restrict__ reluw,
                        const float* __restrict__ fc1b, const float* __restrict__ fc2b,
                        const float* __restrict__ relub,
                        const float* __restrict__ w1rel, const float* __restrict__ w1root,
                        const float* __restrict__ w2rel, const float* __restrict__ w2root,
                        float* __restrict__ vfp, u16* __restrict__ WTin,
                        float* __restrict__ bcomb, u16* __restrict__ WT1, u16* __restrict__ WT2,
                        int* __restrict__ zero_region, int* __restrict__ mark) {
    int b = blockIdx.x, t = threadIdx.x;
    if (b < 6250) {                              // padvf: NN*32 = 1.6M
        int i = b * 256 + t;
        int n = i >> 5, c = i & 31;
        vfp[i] = c < 16 ? vf[n * 16 + c] : 0.f;
    } else if (b < 7050) {                       // win: k = b-6250 in [0,800)
        if (t < 128) {
            int k = b - 6250, c = t;
            float s = 0.f;
            if (k < 768) {
                for (int j = 0; j < 128; ++j) s += fc2w[k * 128 + j] * reluw[(128 + j) * 128 + c];
            } else if (k < 784) {
                int kk = k - 768;
                for (int j = 0; j < 128; ++j) s += fc1w[kk * 128 + j] * reluw[j * 128 + c];
            }
            WTin[c * 800 + k] = f2b(s);
        }
    } else if (b == 7050) {                      // bcomb
        if (t < 128) {
            int c = t;
            float s = relub[c];
            for (int j = 0; j < 128; ++j) {
                s += fc1b[j] * reluw[j * 128 + c];
                s += fc2b[j] * reluw[(128 + j) * 128 + c];
            }
            bcomb[c] = s;
        }
    } else if (b < 7563) {                       // wrg1: s = b-7051 in [0,512)
        if (t < 128) {
            int s = b - 7051, c = t;
            float v = (s < 384) ? w1rel[(size_t)s * 128 + c] : w1root[(size_t)(s - 384) * 128 + c];
            WT1[c * 512 + s] = f2b(v);
        }
    } else if (b < 8075) {                       // wrg2
        if (t < 128) {
            int s = b - 7563, c = t;
            float v = (s < 384) ? w2rel[(size_t)s * 128 + c] : w2root[(size_t)(s - 384) * 128 + c];
            WT2[c * 512 + s] = f2b(v);
        }
    } else if (b < 9052) {                       // zero counters region: 250002 ints
        int i = (b - 8075) * 256 + t;
        if (i < 250002) zero_region[i] = 0;
    } else {                                     // zero mark[NN]
        int i = (b - 9052) * 256 + t;
        if (i < NN) mark[i] = 0;
    }
}

// ---------------- CSR hist + idx mark/compact ----------------

__global__ void k_hist_mark(const int* __restrict__ ei, const int* __restrict__ et,
                            int* __restrict__ deg_node, int* __restrict__ deg_rel,
                            const int* __restrict__ idx, int* __restrict__ mark,
                            int* __restrict__ cnt2, int* __restrict__ list) {
    int b = blockIdx.x;
    if (b < 2344) {
        int e = b * 256 + threadIdx.x;
        if (e < NE) {
            int dst = ei[NE + e];
            int r = et[e];
            atomicAdd(&deg_node[dst], 1);
            atomicAdd(&deg_rel[r * NN + dst], 1);
        }
    } else {
        int i = (b - 2344) * 256 + threadIdx.x;
        if (i < NIDX) {
            int n = idx[i];
            if (atomicExch(&mark[n], 1) == 0) {
                int p = atomicAdd(cnt2, 1);
                list[p] = n;
            }
        }
    }
}

// ---------------- alloc (CSR offsets) + norm ----------------

__global__ void k_alloc_norm(const int* __restrict__ deg_node, int* __restrict__ baseoff,
                             int* __restrict__ counter, const int* __restrict__ deg_rel,
                             float* __restrict__ normf) {
    int b = blockIdx.x;
    if (b < 196) {
        int i = b * 256 + threadIdx.x;
        int lane = threadIdx.x & 63;
        int d = (i < NN) ? deg_node[i] : 0;
        int scan = d;
        for (int off = 1; off < 64; off <<= 1) {
            int t = __shfl_up(scan, off, 64);
            if (lane >= off) scan += t;
        }
        int total = __shfl(scan, 63, 64);
        int wbase = 0;
        if (lane == 63) wbase = atomicAdd(counter, total);
        wbase = __shfl(wbase, 63, 64);
        if (i < NN) baseoff[i] = wbase + scan - d;
    } else {
        int i = (b - 196) * 256 + threadIdx.x;
        if (i < 3 * NN) normf[i] = 1.0f / (float)max(deg_rel[i], 1);
    }
}

__global__ void k_fill(const int* __restrict__ ei, const int* __restrict__ et,
                       const int* __restrict__ baseoff, int* __restrict__ cursor,
                       int* __restrict__ elist) {
    int e = blockIdx.x * 256 + threadIdx.x;
    if (e >= NE) return;
    int dst = ei[NE + e];
    int src = ei[e];
    int r = et[e];
    int pos = atomicAdd(&cursor[dst], 1);
    elist[baseoff[dst] + pos] = src | (r << 20);
}

// ---------------- aggregation (round-11 serial form, measured best) ----------------

__global__ __launch_bounds__(64) void k_agg(const u16* __restrict__ x, u16* __restrict__ A,
                                            const int* __restrict__ elist,
                                            const int* __restrict__ baseoff,
                                            const int* __restrict__ deg_node,
                                            const float* __restrict__ normf) {
    int n = blockIdx.x;
    int lane = threadIdx.x;
    float a0x = 0.f, a0y = 0.f, a1x = 0.f, a1y = 0.f, a2x = 0.f, a2y = 0.f;
    int nb = deg_node[n];
    int b0 = baseoff[n];
    for (int i = 0; i < nb; ++i) {
        int p = elist[b0 + i];
        int src = p & 0xFFFFF;
        int r = p >> 20;
        u32 pair = *(const u32*)&x[(size_t)src * 128 + lane * 2];
        float vx = __uint_as_float((pair & 0xFFFFu) << 16);
        float vy = __uint_as_float((pair >> 16) << 16);
        if (r == 0)      { a0x += vx; a0y += vy; }
        else if (r == 1) { a1x += vx; a1y += vy; }
        else             { a2x += vx; a2y += vy; }
    }
    float n0 = normf[n], n1 = normf[NN + n], n2 = normf[2 * NN + n];
    u32* Ao = (u32*)&A[(size_t)n * 384];
    Ao[lane]        = (u32)f2b(a0x * n0) | ((u32)f2b(a0y * n0) << 16);
    Ao[64 + lane]   = (u32)f2b(a1x * n1) | ((u32)f2b(a1y * n1) << 16);
    Ao[128 + lane]  = (u32)f2b(a2x * n2) | ((u32)f2b(a2y * n2) << 16);
}

// layer-2 aggregation: only rows in list[0..cnt2), output compacted
__global__ __launch_bounds__(64) void k_agg2(const u16* __restrict__ x, u16* __restrict__ A2buf,
                                             const int* __restrict__ elist,
                                             const int* __restrict__ baseoff,
                                             const int* __restrict__ deg_node,
                                             const float* __restrict__ normf,
                                             const int* __restrict__ list,
                                             const int* __restrict__ cnt2) {
    int i = blockIdx.x;
    if (i >= *cnt2) return;
    int n = list[i];
    int lane = threadIdx.x;
    float a0x = 0.f, a0y = 0.f, a1x = 0.f, a1y = 0.f, a2x = 0.f, a2y = 0.f;
    int nb = deg_node[n];
    int b0 = baseoff[n];
    for (int e = 0; e < nb; ++e) {
        int p = elist[b0 + e];
        int src = p & 0xFFFFF;
        int r = p >> 20;
        u32 pair = *(const u32*)&x[(size_t)src * 128 + lane * 2];
        float vx = __uint_as_float((pair & 0xFFFFu) << 16);
        float vy = __uint_as_float((pair >> 16) << 16);
        if (r == 0)      { a0x += vx; a0y += vy; }
        else if (r == 1) { a1x += vx; a1y += vy; }
        else             { a2x += vx; a2y += vy; }
    }
    float n0 = normf[n], n1 = normf[NN + n], n2 = normf[2 * NN + n];
    u32* Ao = (u32*)&A2buf[(size_t)i * 384];
    Ao[lane]        = (u32)f2b(a0x * n0) | ((u32)f2b(a0y * n0) << 16);
    Ao[64 + lane]   = (u32)f2b(a1x * n1) | ((u32)f2b(a1y * n1) << 16);
    Ao[128 + lane]  = (u32)f2b(a2x * n2) | ((u32)f2b(a2y * n2) << 16);
}

// ---------------- GEMM body: BM=64, SUBT k32-subtiles per stage (BK = 32*SUBT),
// 3 LDS buffers, depth-2 prefetch, counted vmcnt at no-drain barriers.
// LIST mode: dynamic N=*cntp, A2/output rows indirected through list[] ----------------

template <typename TA, int K1T, int K2T, int SUBT, bool LRELU, bool LIST>
__device__ __forceinline__ void gemm_body(const TA* __restrict__ A1, int lda1,
                                          const TA* __restrict__ A2, int lda2,
                                          const u16* __restrict__ WT, int ldwt,
                                          const float* __restrict__ bias,
                                          u16* __restrict__ out, int Nin,
                                          const int* __restrict__ list,
                                          const int* __restrict__ cntp) {
    constexpr int KT32 = K1T + K2T;               // k32 tiles; must be multiple of SUBT
    constexpr int NST = KT32 / SUBT;              // pipeline steps
    constexpr int ABYTES = 64 * 32 * (int)sizeof(TA);   // A bytes per k32 sub-tile
    constexpr int SUBB = ABYTES + 8192;           // sub-tile (A + B)
    constexpr int TILEB = SUBT * SUBB;            // per buffer
    constexpr int OPW = SUBT * ((sizeof(TA) == 4) ? 4 : 3);  // DMA instrs per wave per stage
    __shared__ alignas(128) char lds[3][TILEB];

    const int N = LIST ? *cntp : Nin;
    const int m0 = blockIdx.x * 64;
    if (LIST && m0 >= N) return;   // uniform whole-block exit, before any barrier

    const int tid = threadIdx.x;
    const int w = tid >> 6, lane = tid & 63;
    const int wr = w >> 1, wc = w & 1;
    const int lq = lane >> 4, lr = lane & 15;

    auto stage32 = [&](int kt, char* base) {
        if constexpr (sizeof(TA) == 4) {
#pragma unroll
            for (int jj = 0; jj < 2; ++jj) {
                int row = w * 16 + jj * 8 + (lane >> 3);
                int s = lane & 7;
                int chunk = s ^ (row & 7);
                int rg = min(m0 + row, N - 1);
                const float* g;
                if (kt < K1T) g = (const float*)A1 + (size_t)rg * lda1 + kt * 32 + chunk * 4;
                else          g = (const float*)A2 + (size_t)rg * lda2 + (kt - K1T) * 32 + chunk * 4;
                gl_lds16(g, base + w * 2048 + jj * 1024);
            }
        } else {
            int row = w * 16 + (lane >> 2);
            int s = lane & 3;
            int chunk = s ^ ((row >> 1) & 3);
            int rg = min(m0 + row, N - 1);
            const u16* g;
            if (kt < K1T) {
                g = (const u16*)A1 + (size_t)rg * lda1 + kt * 32 + chunk * 8;
            } else {
                int node = LIST ? list[rg] : rg;
                g = (const u16*)A2 + (size_t)node * lda2 + (kt - K1T) * 32 + chunk * 8;
            }
            gl_lds16(g, base + w * 1024);
        }
#pragma unroll
        for (int jj = 0; jj < 2; ++jj) {
            int col = w * 32 + jj * 16 + (lane >> 2);
            int s = lane & 3;
            int chunk = s ^ ((col >> 1) & 3);
            const u16* g = WT + (size_t)col * ldwt + kt * 32 + chunk * 8;
            gl_lds16(g, base + ABYTES + w * 2048 + jj * 1024);
        }
    };
    auto stage = [&](int j) {
        char* bb = lds[j % 3];
#pragma unroll
        for (int s = 0; s < SUBT; ++s) stage32(j * SUBT + s, bb + s * SUBB);
    };

    f32x4 acc[2][4] = {};

    auto compute32 = [&](char* base) {
        s16x8 af[2];
#pragma unroll
        for (int i = 0; i < 2; ++i) {
            int row = wr * 32 + i * 16 + lr;
            if constexpr (sizeof(TA) == 4) {
                int m = row & 7;
                float4 f0 = *(const float4*)(base + row * 128 + (((2 * lq) ^ m) * 16));
                float4 f1 = *(const float4*)(base + row * 128 + (((2 * lq + 1) ^ m) * 16));
                af[i] = pack8(f0, f1);
            } else {
                int sl = lq ^ ((row >> 1) & 3);
                af[i] = *(const s16x8*)(base + row * 64 + sl * 16);
            }
        }
#pragma unroll
        for (int j4 = 0; j4 < 4; ++j4) {
            int col = wc * 64 + j4 * 16 + lr;
            int sl = lq ^ ((col >> 1) & 3);
            s16x8 bf = *(const s16x8*)(base + ABYTES + col * 64 + sl * 16);
#pragma unroll
            for (int i = 0; i < 2; ++i)
                acc[i][j4] = __builtin_amdgcn_mfma_f32_16x16x32_bf16(af[i], bf, acc[i][j4], 0, 0, 0);
        }
    };
    auto compute = [&](int j) {
        char* bb = lds[j % 3];
#pragma unroll
        for (int s = 0; s < SUBT; ++s) compute32(bb + s * SUBB);
    };

    stage(0); stage(1);
#pragma unroll 1
    for (int j = 0; j < NST - 1; ++j) {
        vmwait<OPW>();             // stage(j) landed; stage(j+1) stays in flight
        barrier_nodrains();
        if (j + 2 < NST) stage(j + 2);
        compute(j);
    }
    vmwait<0>();
    barrier_nodrains();
    compute(NST - 1);

#pragma unroll
    for (int i = 0; i < 2; ++i) {
#pragma unroll
        for (int q = 0; q < 4; ++q) {
            int grow = m0 + wr * 32 + i * 16 + lq * 4 + q;
            if (grow < N) {
                int orow = LIST ? list[grow] : grow;
#pragma unroll
                for (int j = 0; j < 4; ++j) {
                    int col = wc * 64 + j * 16 + lr;
                    float v = acc[i][j][q] + bias[col];
                    if (LRELU) v = v > 0.f ? v : 0.01f * v;
                    out[(size_t)orow * 128 + col] = f2b(v);
                }
            }
        }
    }
}

__global__ __launch_bounds__(256) void k_gemm_in(const float* __restrict__ A1, int lda1,
                                                 const float* __restrict__ A2, int lda2,
                                                 const u16* __restrict__ WT, int ldwt,
                                                 const float* __restrict__ bias,
                                                 u16* __restrict__ out, int N) {
    gemm_body<float, 24, 1, 1, true, false>(A1, lda1, A2, lda2, WT, ldwt, bias, out, N, nullptr, nullptr);
}
__global__ __launch_bounds__(256) void k_gemm_r1(const u16* __restrict__ A1, int lda1,
                                                 const u16* __restrict__ A2, int lda2,
                                                 const u16* __restrict__ WT, int ldwt,
                                                 const float* __restrict__ bias,
                                                 u16* __restrict__ out, int N) {
    gemm_body<u16, 12, 4, 4, false, false>(A1, lda1, A2, lda2, WT, ldwt, bias, out, N, nullptr, nullptr);
}
__global__ __launch_bounds__(256) void k_gemm_r2(const u16* __restrict__ A1, int lda1,
                                                 const u16* __restrict__ A2, int lda2,
                                                 const u16* __restrict__ WT, int ldwt,
                                                 const float* __restrict__ bias,
                                                 u16* __restrict__ out,
                                                 const int* __restrict__ list,
                                                 const int* __restrict__ cnt2) {
    gemm_body<u16, 12, 4, 4, false, true>(A1, lda1, A2, lda2, WT, ldwt, bias, out, NIDX, list, cnt2);
}

// ---------------- final gather + classifier ----------------

__global__ __launch_bounds__(256) void k_out(const u16* __restrict__ h, const int* __restrict__ idx,
                                             const float* __restrict__ fc3w,
                                             const float* __restrict__ fc3b,
                                             float* __restrict__ out, int M) {
    int w = threadIdx.x >> 6;
    int lane = threadIdx.x & 63;
    int row = blockIdx.x * 4 + w;
    if (row >= M) return;
    int n = idx[row];
    u32 pair = *(const u32*)&h[(size_t)n * 128 + lane * 2];
    float v0 = __uint_as_float((pair & 0xFFFFu) << 16);
    float v1 = __uint_as_float((pair >> 16) << 16);
    float4 wv = *(const float4*)&fc3w[lane * 4];
    float s0 = v0 * wv.x + v1 * wv.z;
    float s1 = v0 * wv.y + v1 * wv.w;
    for (int off = 32; off >= 1; off >>= 1) {
        s0 += __shfl_xor(s0, off, 64);
        s1 += __shfl_xor(s1, off, 64);
    }
    if (lane == 0) {
        out[row * 2] = s0 + fc3b[0];
        out[row * 2 + 1] = s1 + fc3b[1];
    }
}

// ---------------- launch ----------------

extern "C" void kernel_launch(void* const* d_in, const int* in_sizes, int n_in,
                              void* d_out, int out_size, void* d_ws, size_t ws_size,
                              hipStream_t stream) {
    const float* vf    = (const float*)d_in[0];
    const float* tf    = (const float*)d_in[1];
    const float* fc1w  = (const float*)d_in[2];
    const float* fc1b  = (const float*)d_in[3];
    const float* fc2w  = (const float*)d_in[4];
    const float* fc2b  = (const float*)d_in[5];
    const float* reluw = (const float*)d_in[6];
    const float* relub = (const float*)d_in[7];
    const float* w1rel = (const float*)d_in[8];
    const float* w1root= (const float*)d_in[9];
    const float* b1    = (const float*)d_in[10];
    const float* w2rel = (const float*)d_in[11];
    const float* w2root= (const float*)d_in[12];
    const float* b2    = (const float*)d_in[13];
    const float* fc3w  = (const float*)d_in[14];
    const float* fc3b  = (const float*)d_in[15];
    const int* ei      = (const int*)d_in[16];
    const int* et      = (const int*)d_in[17];
    const int* idx     = (const int*)d_in[18];
    float* out = (float*)d_out;

    char* W = (char*)d_ws;
    const size_t OFF_WTIN  = 0;         // 204800
    const size_t OFF_WT1   = 204800;    // 131072
    const size_t OFF_WT2   = 335872;    // 131072
    const size_t OFF_BCOMB = 466944;    // 512
    const size_t OFF_DEGN  = 467456;    // zero region: degn|cur|degr|cnt|cnt2 = 250002 ints
    const size_t OFF_CUR   = 667456;
    const size_t OFF_DEGR  = 867456;
    const size_t OFF_CNT   = 1467456;
    const size_t OFF_CNT2  = 1467460;
    const size_t OFF_BASE  = 1467712;
    const size_t OFF_NORM  = 1667712;
    const size_t OFF_ELIST = 2267712;
    const size_t OFF_A     = 4667712;
    const size_t OFF_H0    = 43067712;
    const size_t OFF_H1    = 55867712;
    const size_t OFF_H2    = 68667712;
    const size_t OFF_VFPAD = 81467712;  // 6400000
    const size_t OFF_LIST  = 87867712;  // 40000
    const size_t OFF_A2    = 87907712;  // 7680000
    const size_t OFF_MARK  = 95587712;  // 200000 -> total 95787712

    u16* WTin   = (u16*)(W + OFF_WTIN);
    u16* WT1    = (u16*)(W + OFF_WT1);
    u16* WT2    = (u16*)(W + OFF_WT2);
    float* bcomb= (float*)(W + OFF_BCOMB);
    int* degn   = (int*)(W + OFF_DEGN);
    int* cur    = (int*)(W + OFF_CUR);
    int* degr   = (int*)(W + OFF_DEGR);
    int* cnt    = (int*)(W + OFF_CNT);
    int* cnt2   = (int*)(W + OFF_CNT2);
    int* base   = (int*)(W + OFF_BASE);
    float* normf= (float*)(W + OFF_NORM);
    int* elist  = (int*)(W + OFF_ELIST);
    u16* Abuf   = (u16*)(W + OFF_A);
    u16* h0     = (u16*)(W + OFF_H0);
    u16* h1     = (u16*)(W + OFF_H1);
    u16* h2     = (u16*)(W + OFF_H2);
    float* vfp  = (float*)(W + OFF_VFPAD);
    int* list   = (int*)(W + OFF_LIST);
    u16* A2buf  = (u16*)(W + OFF_A2);
    int* mark   = (int*)(W + OFF_MARK);

    const int GRID_GEMM = (NN + 63) / 64;      // 782
    const int GRID_G2   = (NIDX + 63) / 64;    // 157

    // 1. fused setup (padvf | win | bcomb | wrg1 | wrg2 | zero counters | zero mark)
    k_setup<<<9248, 256, 0, stream>>>(vf, fc1w, fc2w, reluw, fc1b, fc2b, relub,
                                      w1rel, w1root, w2rel, w2root,
                                      vfp, WTin, bcomb, WT1, WT2, degn, mark);

    // 2. fused input GEMM (BK=32, 25 steps, 48KB LDS, 3 blk/CU — best measured)
    k_gemm_in<<<GRID_GEMM, 256, 0, stream>>>(tf, 768, vfp, 32, WTin, 800, bcomb, h0, NN);

    // 3. CSR build + idx mark/compact
    k_hist_mark<<<2384, 256, 0, stream>>>(ei, et, degn, degr, idx, mark, cnt2, list);
    k_alloc_norm<<<782, 256, 0, stream>>>(degn, base, cnt, degr, normf);
    k_fill<<<(NE + 255) / 256, 256, 0, stream>>>(ei, et, base, cur, elist);

    // 4. RGCN layer 1 (full; BK=128: 4 steps, 144KB LDS)
    k_agg<<<NN, 64, 0, stream>>>(h0, Abuf, elist, base, degn, normf);
    k_gemm_r1<<<GRID_GEMM, 256, 0, stream>>>(Abuf, 384, h0, 128, WT1, 512, b1, h1, NN);

    // 5. RGCN layer 2 (only idx rows; BK=128)
    k_agg2<<<NIDX, 64, 0, stream>>>(h1, A2buf, elist, base, degn, normf, list, cnt2);
    k_gemm_r2<<<GRID_G2, 256, 0, stream>>>(A2buf, 384, h1, 128, WT2, 512, b2, h2, list, cnt2);

    // 6. classifier on gathered rows
    k_out<<<(NIDX + 3) / 4, 256, 0, stream>>>(h2, idx, fc3w, fc3b, out, NIDX);
}

// Round 18
// 229.931 us; speedup vs baseline: 1.1229x; 1.0908x over previous
//
#include <hip/hip_runtime.h>
#include <hip/hip_bf16.h>

typedef __attribute__((ext_vector_type(8))) short s16x8;
typedef __attribute__((ext_vector_type(4))) float f32x4;
typedef unsigned short u16;
typedef unsigned int u32;

constexpr int NN = 50000;
constexpr int NE = 600000;
constexpr int NIDX = 10000;

__device__ inline u16 f2b(float x) {
    __hip_bfloat16 h = __float2bfloat16(x);
    return *(u16*)&h;
}

__device__ inline s16x8 pack8(float4 a, float4 b) {
    s16x8 r;
    r[0] = (short)f2b(a.x); r[1] = (short)f2b(a.y);
    r[2] = (short)f2b(a.z); r[3] = (short)f2b(a.w);
    r[4] = (short)f2b(b.x); r[5] = (short)f2b(b.y);
    r[6] = (short)f2b(b.z); r[7] = (short)f2b(b.w);
    return r;
}

// async global->LDS DMA, 16B per lane: LDS dst = wave-uniform base + lane*16.
__device__ inline void gl_lds16(const void* gptr, void* lptr) {
    __builtin_amdgcn_global_load_lds(
        (const __attribute__((address_space(1))) char*)gptr,
        (__attribute__((address_space(3))) char*)lptr, 16, 0, 0);
}

template <int N> __device__ inline void vmwait() {
    asm volatile("s_waitcnt vmcnt(%0)" :: "n"(N) : "memory");
}
__device__ inline void barrier_nodrains() {
    __builtin_amdgcn_sched_barrier(0);
    __builtin_amdgcn_s_barrier();
    __builtin_amdgcn_sched_barrier(0);
}

// ---------------- setup: padvf | win | bcomb | zero counters | zero mark ----------------
// (zeroing MUST precede the hist/mark atomics, which now live in the fused gin kernel)

__global__ void k_setup(const float* __restrict__ vf,
                        const float* __restrict__ fc1w, const float* __restrict__ fc2w,
                        const float* __restrict__ reluw,
                        const float* __restrict__ fc1b, const float* __restrict__ fc2b,
                        const float* __restrict__ relub,
                        float* __restrict__ vfp, u16* __restrict__ WTin,
                        float* __restrict__ bcomb,
                        int* __restrict__ zero_region, int* __restrict__ mark) {
    int b = blockIdx.x, t = threadIdx.x;
    if (b < 6250) {                              // padvf: NN*32 = 1.6M
        int i = b * 256 + t;
        int n = i >> 5, c = i & 31;
        vfp[i] = c < 16 ? vf[n * 16 + c] : 0.f;
    } else if (b < 7050) {                       // win: k = b-6250 in [0,800)
        if (t < 128) {
            int k = b - 6250, c = t;
            float s = 0.f;
            if (k < 768) {
                for (int j = 0; j < 128; ++j) s += fc2w[k * 128 + j] * reluw[(128 + j) * 128 + c];
            } else if (k < 784) {
                int kk = k - 768;
                for (int j = 0; j < 128; ++j) s += fc1w[kk * 128 + j] * reluw[j * 128 + c];
            }
            WTin[c * 800 + k] = f2b(s);
        }
    } else if (b == 7050) {                      // bcomb
        if (t < 128) {
            int c = t;
            float s = relub[c];
            for (int j = 0; j < 128; ++j) {
                s += fc1b[j] * reluw[j * 128 + c];
                s += fc2b[j] * reluw[(128 + j) * 128 + c];
            }
            bcomb[c] = s;
        }
    } else if (b < 8028) {                       // zero counters region: 250002 ints
        int i = (b - 7051) * 256 + t;
        if (i < 250002) zero_region[i] = 0;
    } else {                                     // zero mark[NN]
        int i = (b - 8028) * 256 + t;
        if (i < NN) mark[i] = 0;
    }
}

// ---------------- alloc (CSR offsets) + norm ----------------

__global__ void k_alloc_norm(const int* __restrict__ deg_node, int* __restrict__ baseoff,
                             int* __restrict__ counter, const int* __restrict__ deg_rel,
                             float* __restrict__ normf) {
    int b = blockIdx.x;
    if (b < 196) {
        int i = b * 256 + threadIdx.x;
        int lane = threadIdx.x & 63;
        int d = (i < NN) ? deg_node[i] : 0;
        int scan = d;
        for (int off = 1; off < 64; off <<= 1) {
            int t = __shfl_up(scan, off, 64);
            if (lane >= off) scan += t;
        }
        int total = __shfl(scan, 63, 64);
        int wbase = 0;
        if (lane == 63) wbase = atomicAdd(counter, total);
        wbase = __shfl(wbase, 63, 64);
        if (i < NN) baseoff[i] = wbase + scan - d;
    } else {
        int i = (b - 196) * 256 + threadIdx.x;
        if (i < 3 * NN) normf[i] = 1.0f / (float)max(deg_rel[i], 1);
    }
}

__global__ void k_fill(const int* __restrict__ ei, const int* __restrict__ et,
                       const int* __restrict__ baseoff, int* __restrict__ cursor,
                       int* __restrict__ elist) {
    int e = blockIdx.x * 256 + threadIdx.x;
    if (e >= NE) return;
    int dst = ei[NE + e];
    int src = ei[e];
    int r = et[e];
    int pos = atomicAdd(&cursor[dst], 1);
    elist[baseoff[dst] + pos] = src | (r << 20);
}

// ---------------- aggregation (round-11 serial form, measured best) ----------------

__global__ __launch_bounds__(64) void k_agg(const u16* __restrict__ x, u16* __restrict__ A,
                                            const int* __restrict__ elist,
                                            const int* __restrict__ baseoff,
                                            const int* __restrict__ deg_node,
                                            const float* __restrict__ normf) {
    int n = blockIdx.x;
    int lane = threadIdx.x;
    float a0x = 0.f, a0y = 0.f, a1x = 0.f, a1y = 0.f, a2x = 0.f, a2y = 0.f;
    int nb = deg_node[n];
    int b0 = baseoff[n];
    for (int i = 0; i < nb; ++i) {
        int p = elist[b0 + i];
        int src = p & 0xFFFFF;
        int r = p >> 20;
        u32 pair = *(const u32*)&x[(size_t)src * 128 + lane * 2];
        float vx = __uint_as_float((pair & 0xFFFFu) << 16);
        float vy = __uint_as_float((pair >> 16) << 16);
        if (r == 0)      { a0x += vx; a0y += vy; }
        else if (r == 1) { a1x += vx; a1y += vy; }
        else             { a2x += vx; a2y += vy; }
    }
    float n0 = normf[n], n1 = normf[NN + n], n2 = normf[2 * NN + n];
    u32* Ao = (u32*)&A[(size_t)n * 384];
    Ao[lane]        = (u32)f2b(a0x * n0) | ((u32)f2b(a0y * n0) << 16);
    Ao[64 + lane]   = (u32)f2b(a1x * n1) | ((u32)f2b(a1y * n1) << 16);
    Ao[128 + lane]  = (u32)f2b(a2x * n2) | ((u32)f2b(a2y * n2) << 16);
}

// layer-2 aggregation: only rows in list[0..cnt2), output compacted
__global__ __launch_bounds__(64) void k_agg2(const u16* __restrict__ x, u16* __restrict__ A2buf,
                                             const int* __restrict__ elist,
                                             const int* __restrict__ baseoff,
                                             const int* __restrict__ deg_node,
                                             const float* __restrict__ normf,
                                             const int* __restrict__ list,
                                             const int* __restrict__ cnt2) {
    int i = blockIdx.x;
    if (i >= *cnt2) return;
    int n = list[i];
    int lane = threadIdx.x;
    float a0x = 0.f, a0y = 0.f, a1x = 0.f, a1y = 0.f, a2x = 0.f, a2y = 0.f;
    int nb = deg_node[n];
    int b0 = baseoff[n];
    for (int e = 0; e < nb; ++e) {
        int p = elist[b0 + e];
        int src = p & 0xFFFFF;
        int r = p >> 20;
        u32 pair = *(const u32*)&x[(size_t)src * 128 + lane * 2];
        float vx = __uint_as_float((pair & 0xFFFFu) << 16);
        float vy = __uint_as_float((pair >> 16) << 16);
        if (r == 0)      { a0x += vx; a0y += vy; }
        else if (r == 1) { a1x += vx; a1y += vy; }
        else             { a2x += vx; a2y += vy; }
    }
    float n0 = normf[n], n1 = normf[NN + n], n2 = normf[2 * NN + n];
    u32* Ao = (u32*)&A2buf[(size_t)i * 384];
    Ao[lane]        = (u32)f2b(a0x * n0) | ((u32)f2b(a0y * n0) << 16);
    Ao[64 + lane]   = (u32)f2b(a1x * n1) | ((u32)f2b(a1y * n1) << 16);
    Ao[128 + lane]  = (u32)f2b(a2x * n2) | ((u32)f2b(a2y * n2) << 16);
}

// ---------------- GEMM body: BM=64, SUBT k32-subtiles per stage (BK = 32*SUBT),
// 3 LDS buffers, depth-2 prefetch, counted vmcnt at no-drain barriers.
// LIST mode: dynamic N=*cntp, A2/output rows indirected through list[] ----------------

template <typename TA, int K1T, int K2T, int SUBT, bool LRELU, bool LIST>
__device__ __forceinline__ void gemm_body(int bid,
                                          const TA* __restrict__ A1, int lda1,
                                          const TA* __restrict__ A2, int lda2,
                                          const u16* __restrict__ WT, int ldwt,
                                          const float* __restrict__ bias,
                                          u16* __restrict__ out, int Nin,
                                          const int* __restrict__ list,
                                          const int* __restrict__ cntp) {
    constexpr int KT32 = K1T + K2T;
    constexpr int NST = KT32 / SUBT;
    constexpr int ABYTES = 64 * 32 * (int)sizeof(TA);
    constexpr int SUBB = ABYTES + 8192;
    constexpr int TILEB = SUBT * SUBB;
    constexpr int OPW = SUBT * ((sizeof(TA) == 4) ? 4 : 3);
    __shared__ alignas(128) char lds[3][TILEB];

    const int N = LIST ? *cntp : Nin;
    const int m0 = bid * 64;
    if (LIST && m0 >= N) return;

    const int tid = threadIdx.x;
    const int w = tid >> 6, lane = tid & 63;
    const int wr = w >> 1, wc = w & 1;
    const int lq = lane >> 4, lr = lane & 15;

    auto stage32 = [&](int kt, char* base) {
        if constexpr (sizeof(TA) == 4) {
#pragma unroll
            for (int jj = 0; jj < 2; ++jj) {
                int row = w * 16 + jj * 8 + (lane >> 3);
                int s = lane & 7;
                int chunk = s ^ (row & 7);
                int rg = min(m0 + row, N - 1);
                const float* g;
                if (kt < K1T) g = (const float*)A1 + (size_t)rg * lda1 + kt * 32 + chunk * 4;
                else          g = (const float*)A2 + (size_t)rg * lda2 + (kt - K1T) * 32 + chunk * 4;
                gl_lds16(g, base + w * 2048 + jj * 1024);
            }
        } else {
            int row = w * 16 + (lane >> 2);
            int s = lane & 3;
            int chunk = s ^ ((row >> 1) & 3);
            int rg = min(m0 + row, N - 1);
            const u16* g;
            if (kt < K1T) {
                g = (const u16*)A1 + (size_t)rg * lda1 + kt * 32 + chunk * 8;
            } else {
                int node = LIST ? list[rg] : rg;
                g = (const u16*)A2 + (size_t)node * lda2 + (kt - K1T) * 32 + chunk * 8;
            }
            gl_lds16(g, base + w * 1024);
        }
#pragma unroll
        for (int jj = 0; jj < 2; ++jj) {
            int col = w * 32 + jj * 16 + (lane >> 2);
            int s = lane & 3;
            int chunk = s ^ ((col >> 1) & 3);
            const u16* g = WT + (size_t)col * ldwt + kt * 32 + chunk * 8;
            gl_lds16(g, base + ABYTES + w * 2048 + jj * 1024);
        }
    };
    auto stage = [&](int j) {
        char* bb = lds[j % 3];
#pragma unroll
        for (int s = 0; s < SUBT; ++s) stage32(j * SUBT + s, bb + s * SUBB);
    };

    f32x4 acc[2][4] = {};

    auto compute32 = [&](char* base) {
        s16x8 af[2];
#pragma unroll
        for (int i = 0; i < 2; ++i) {
            int row = wr * 32 + i * 16 + lr;
            if constexpr (sizeof(TA) == 4) {
                int m = row & 7;
                float4 f0 = *(const float4*)(base + row * 128 + (((2 * lq) ^ m) * 16));
                float4 f1 = *(const float4*)(base + row * 128 + (((2 * lq + 1) ^ m) * 16));
                af[i] = pack8(f0, f1);
            } else {
                int sl = lq ^ ((row >> 1) & 3);
                af[i] = *(const s16x8*)(base + row * 64 + sl * 16);
            }
        }
#pragma unroll
        for (int j4 = 0; j4 < 4; ++j4) {
            int col = wc * 64 + j4 * 16 + lr;
            int sl = lq ^ ((col >> 1) & 3);
            s16x8 bf = *(const s16x8*)(base + ABYTES + col * 64 + sl * 16);
#pragma unroll
            for (int i = 0; i < 2; ++i)
                acc[i][j4] = __builtin_amdgcn_mfma_f32_16x16x32_bf16(af[i], bf, acc[i][j4], 0, 0, 0);
        }
    };
    auto compute = [&](int j) {
        char* bb = lds[j % 3];
#pragma unroll
        for (int s = 0; s < SUBT; ++s) compute32(bb + s * SUBB);
    };

    stage(0); stage(1);
#pragma unroll 1
    for (int j = 0; j < NST - 1; ++j) {
        vmwait<OPW>();
        barrier_nodrains();
        if (j + 2 < NST) stage(j + 2);
        compute(j);
    }
    vmwait<0>();
    barrier_nodrains();
    compute(NST - 1);

#pragma unroll
    for (int i = 0; i < 2; ++i) {
#pragma unroll
        for (int q = 0; q < 4; ++q) {
            int grow = m0 + wr * 32 + i * 16 + lq * 4 + q;
            if (grow < N) {
                int orow = LIST ? list[grow] : grow;
#pragma unroll
                for (int j = 0; j < 4; ++j) {
                    int col = wc * 64 + j * 16 + lr;
                    float v = acc[i][j][q] + bias[col];
                    if (LRELU) v = v > 0.f ? v : 0.01f * v;
                    out[(size_t)orow * 128 + col] = f2b(v);
                }
            }
        }
    }
}

// ---------------- fused input GEMM + (independent) hist/mark/wrg work ----------------
// Block ranges: [0,782) gemm | [782,3126) hist | [3126,3166) idx mark/compact
// | [3166,3678) wrg1 | [3678,4190) wrg2. The aux blocks co-execute in the
// latency-bound gemm's idle issue slots. Zeroing of degn/degr/mark happened in
// k_setup (prior kernel) — no intra-kernel ordering needed.

__global__ __launch_bounds__(256) void k_gin_fused(
        const float* __restrict__ A1, int lda1,
        const float* __restrict__ A2, int lda2,
        const u16* __restrict__ WT, int ldwt,
        const float* __restrict__ bias, u16* __restrict__ out, int N,
        const int* __restrict__ ei, const int* __restrict__ et,
        int* __restrict__ deg_node, int* __restrict__ deg_rel,
        const int* __restrict__ idx, int* __restrict__ mark,
        int* __restrict__ cnt2, int* __restrict__ list,
        const float* __restrict__ w1rel, const float* __restrict__ w1root,
        const float* __restrict__ w2rel, const float* __restrict__ w2root,
        u16* __restrict__ WT1, u16* __restrict__ WT2) {
    int b = blockIdx.x, t = threadIdx.x;
    if (b < 782) {
        gemm_body<float, 24, 1, 1, true, false>(b, A1, lda1, A2, lda2, WT, ldwt,
                                                bias, out, N, nullptr, nullptr);
    } else if (b < 3126) {
        int e = (b - 782) * 256 + t;
        if (e < NE) {
            int dst = ei[NE + e];
            int r = et[e];
            atomicAdd(&deg_node[dst], 1);
            atomicAdd(&deg_rel[r * NN + dst], 1);
        }
    } else if (b < 3166) {
        int i = (b - 3126) * 256 + t;
        if (i < NIDX) {
            int n = idx[i];
            if (atomicExch(&mark[n], 1) == 0) {
                int p = atomicAdd(cnt2, 1);
                list[p] = n;
            }
        }
    } else if (b < 3678) {
        if (t < 128) {
            int s = b - 3166, c = t;
            float v = (s < 384) ? w1rel[(size_t)s * 128 + c] : w1root[(size_t)(s - 384) * 128 + c];
            WT1[c * 512 + s] = f2b(v);
        }
    } else {
        if (t < 128) {
            int s = b - 3678, c = t;
            float v = (s < 384) ? w2rel[(size_t)s * 128 + c] : w2root[(size_t)(s - 384) * 128 + c];
            WT2[c * 512 + s] = f2b(v);
        }
    }
}

__global__ __launch_bounds__(256) void k_gemm_r1(const u16* __restrict__ A1, int lda1,
                                                 const u16* __restrict__ A2, int lda2,
                                                 const u16* __restrict__ WT, int ldwt,
                                                 const float* __restrict__ bias,
                                                 u16* __restrict__ out, int N) {
    gemm_body<u16, 12, 4, 1, false, false>(blockIdx.x, A1, lda1, A2, lda2, WT, ldwt,
                                           bias, out, N, nullptr, nullptr);
}
__global__ __launch_bounds__(256) void k_gemm_r2(const u16* __restrict__ A1, int lda1,
                                                 const u16* __restrict__ A2, int lda2,
                                                 const u16* __restrict__ WT, int ldwt,
                                                 const float* __restrict__ bias,
                                                 u16* __restrict__ out,
                                                 const int* __restrict__ list,
                                                 const int* __restrict__ cnt2) {
    gemm_body<u16, 12, 4, 1, false, true>(blockIdx.x, A1, lda1, A2, lda2, WT, ldwt,
                                          bias, out, NIDX, list, cnt2);
}

// ---------------- final gather + classifier ----------------

__global__ __launch_bounds__(256) void k_out(const u16* __restrict__ h, const int* __restrict__ idx,
                                             const float* __restrict__ fc3w,
                                             const float* __restrict__ fc3b,
                                             float* __restrict__ out, int M) {
    int w = threadIdx.x >> 6;
    int lane = threadIdx.x & 63;
    int row = blockIdx.x * 4 + w;
    if (row >= M) return;
    int n = idx[row];
    u32 pair = *(const u32*)&h[(size_t)n * 128 + lane * 2];
    float v0 = __uint_as_float((pair & 0xFFFFu) << 16);
    float v1 = __uint_as_float((pair >> 16) << 16);
    float4 wv = *(const float4*)&fc3w[lane * 4];
    float s0 = v0 * wv.x + v1 * wv.z;
    float s1 = v0 * wv.y + v1 * wv.w;
    for (int off = 32; off >= 1; off >>= 1) {
        s0 += __shfl_xor(s0, off, 64);
        s1 += __shfl_xor(s1, off, 64);
    }
    if (lane == 0) {
        out[row * 2] = s0 + fc3b[0];
        out[row * 2 + 1] = s1 + fc3b[1];
    }
}

// ---------------- launch ----------------

extern "C" void kernel_launch(void* const* d_in, const int* in_sizes, int n_in,
                              void* d_out, int out_size, void* d_ws, size_t ws_size,
                              hipStream_t stream) {
    const float* vf    = (const float*)d_in[0];
    const float* tf    = (const float*)d_in[1];
    const float* fc1w  = (const float*)d_in[2];
    const float* fc1b  = (const float*)d_in[3];
    const float* fc2w  = (const float*)d_in[4];
    const float* fc2b  = (const float*)d_in[5];
    const float* reluw = (const float*)d_in[6];
    const float* relub = (const float*)d_in[7];
    const float* w1rel = (const float*)d_in[8];
    const float* w1root= (const float*)d_in[9];
    const float* b1    = (const float*)d_in[10];
    const float* w2rel = (const float*)d_in[11];
    const float* w2root= (const float*)d_in[12];
    const float* b2    = (const float*)d_in[13];
    const float* fc3w  = (const float*)d_in[14];
    const float* fc3b  = (const float*)d_in[15];
    const int* ei      = (const int*)d_in[16];
    const int* et      = (const int*)d_in[17];
    const int* idx     = (const int*)d_in[18];
    float* out = (float*)d_out;

    char* W = (char*)d_ws;
    const size_t OFF_WTIN  = 0;         // 204800
    const size_t OFF_WT1   = 204800;    // 131072
    const size_t OFF_WT2   = 335872;    // 131072
    const size_t OFF_BCOMB = 466944;    // 512
    const size_t OFF_DEGN  = 467456;    // zero region: degn|cur|degr|cnt|cnt2 = 250002 ints
    const size_t OFF_CUR   = 667456;
    const size_t OFF_DEGR  = 867456;
    const size_t OFF_CNT   = 1467456;
    const size_t OFF_CNT2  = 1467460;
    const size_t OFF_BASE  = 1467712;
    const size_t OFF_NORM  = 1667712;
    const size_t OFF_ELIST = 2267712;
    const size_t OFF_A     = 4667712;
    const size_t OFF_H0    = 43067712;
    const size_t OFF_H1    = 55867712;
    const size_t OFF_H2    = 68667712;
    const size_t OFF_VFPAD = 81467712;  // 6400000
    const size_t OFF_LIST  = 87867712;  // 40000
    const size_t OFF_A2    = 87907712;  // 7680000
    const size_t OFF_MARK  = 95587712;  // 200000 -> total 95787712

    u16* WTin   = (u16*)(W + OFF_WTIN);
    u16* WT1    = (u16*)(W + OFF_WT1);
    u16* WT2    = (u16*)(W + OFF_WT2);
    float* bcomb= (float*)(W + OFF_BCOMB);
    int* degn   = (int*)(W + OFF_DEGN);
    int* cur    = (int*)(W + OFF_CUR);
    int* degr   = (int*)(W + OFF_DEGR);
    int* cnt    = (int*)(W + OFF_CNT);
    int* cnt2   = (int*)(W + OFF_CNT2);
    int* base   = (int*)(W + OFF_BASE);
    float* normf= (float*)(W + OFF_NORM);
    int* elist  = (int*)(W + OFF_ELIST);
    u16* Abuf   = (u16*)(W + OFF_A);
    u16* h0     = (u16*)(W + OFF_H0);
    u16* h1     = (u16*)(W + OFF_H1);
    u16* h2     = (u16*)(W + OFF_H2);
    float* vfp  = (float*)(W + OFF_VFPAD);
    int* list   = (int*)(W + OFF_LIST);
    u16* A2buf  = (u16*)(W + OFF_A2);
    int* mark   = (int*)(W + OFF_MARK);

    const int GRID_GEMM = (NN + 63) / 64;      // 782
    const int GRID_G2   = (NIDX + 63) / 64;    // 157

    // 1. setup (padvf | win | bcomb | zero counters | zero mark)
    k_setup<<<8224, 256, 0, stream>>>(vf, fc1w, fc2w, reluw, fc1b, fc2b, relub,
                                      vfp, WTin, bcomb, degn, mark);

    // 2. fused input GEMM + hist + idx-compact + wrg1/wrg2 (independent work
    //    co-executes in the latency-bound GEMM's idle slots)
    k_gin_fused<<<4190, 256, 0, stream>>>(tf, 768, vfp, 32, WTin, 800, bcomb, h0, NN,
                                          ei, et, degn, degr, idx, mark, cnt2, list,
                                          w1rel, w1root, w2rel, w2root, WT1, WT2);

    // 3. CSR offsets + norm, then fill (depend on hist)
    k_alloc_norm<<<782, 256, 0, stream>>>(degn, base, cnt, degr, normf);
    k_fill<<<(NE + 255) / 256, 256, 0, stream>>>(ei, et, base, cur, elist);

    // 4. RGCN layer 1 (full; BK=32 — round-14 measured best)
    k_agg<<<NN, 64, 0, stream>>>(h0, Abuf, elist, base, degn, normf);
    k_gemm_r1<<<GRID_GEMM, 256, 0, stream>>>(Abuf, 384, h0, 128, WT1, 512, b1, h1, NN);

    // 5. RGCN layer 2 (only idx rows; BK=32)
    k_agg2<<<NIDX, 64, 0, stream>>>(h1, A2buf, elist, base, degn, normf, list, cnt2);
    k_gemm_r2<<<GRID_G2, 256, 0, stream>>>(A2buf, 384, h1, 128, WT2, 512, b2, h2, list, cnt2);

    // 6. classifier on gathered rows
    k_out<<<(NIDX + 3) / 4, 256, 0, stream>>>(h2, idx, fc3w, fc3b, out, NIDX);
}